// Round 3
// baseline (147.990 us; speedup 1.0000x reference)
//
#include <hip/hip_runtime.h>

// N=512, D=512 pairwise scorer, all f32.
// left = E@W1[:D]; right = E@W1[D:]+b1; h = left[i]+right[j]; LN(D); GELU; @W2+b2; sigmoid.
// LN stats decompose over RAW (uncentered) rows:
//   var_h = var_l[i] + var_r[j] + 2*(dot_raw(i,j)/D - ml[i]*mr[j])
//   x_k   = ((l_k + r_k) - ml - mr) * rstd * g_k + be_k
// so no centering pass is needed: k_pair computes per-row mean/var from its
// resident LDS tiles. Two kernels total. Never materialize [N,N,D].

#define N_ 512
#define D_ 512

// ---------------- K1: left/right GEMMs ----------------
// 256 blocks = 32 rowgrps (16 rows) x 8 ccgrps (128 combined cols of 1024).
// 512 thr (8 waves = 2/SIMD): t&31 -> col quad, t>>5 -> row. 1 row x 4 cols
// per thread: 16 FMA per (1 ds_read_b128 + 4 global dwordx4), 16 loads in
// flight per unroll-4 body.
__global__ __launch_bounds__(512) void k_gemm(const float* __restrict__ E,
                                              const float* __restrict__ W1,
                                              const float* __restrict__ b1,
                                              float* __restrict__ W /* [1024][512] */) {
    __shared__ float e[16][516];  // 516 mod 32 = 4
    const int t = threadIdx.x;
    const int cc = (blockIdx.x & 7) * 128;     // combined col base (0..896)
    const int r0 = (blockIdx.x >> 3) * 16;
    const int half = cc >> 9;
    const int c = (cc & 511) + (t & 31) * 4;
    const int rp = t >> 5;                     // 0..15

    for (int x = t; x < 16 * 128; x += 512) {
        int r = x >> 7, c4 = (x & 127) << 2;
        *(float4*)&e[r][c4] = *(const float4*)&E[(r0 + r) * D_ + c4];
    }
    __syncthreads();

    const float* __restrict__ wp = W1 + (half << 18) + c;
    float4 a0 = {0.f, 0.f, 0.f, 0.f};
#pragma unroll 4
    for (int k = 0; k < D_; k += 4) {
        float4 e0 = *(float4*)&e[rp][k];
        float4 wa = *(const float4*)(wp + ((k + 0) << 9));
        float4 wb = *(const float4*)(wp + ((k + 1) << 9));
        float4 wc = *(const float4*)(wp + ((k + 2) << 9));
        float4 wd = *(const float4*)(wp + ((k + 3) << 9));
        a0.x = fmaf(e0.x, wa.x, a0.x); a0.y = fmaf(e0.x, wa.y, a0.y);
        a0.z = fmaf(e0.x, wa.z, a0.z); a0.w = fmaf(e0.x, wa.w, a0.w);
        a0.x = fmaf(e0.y, wb.x, a0.x); a0.y = fmaf(e0.y, wb.y, a0.y);
        a0.z = fmaf(e0.y, wb.z, a0.z); a0.w = fmaf(e0.y, wb.w, a0.w);
        a0.x = fmaf(e0.z, wc.x, a0.x); a0.y = fmaf(e0.z, wc.y, a0.y);
        a0.z = fmaf(e0.z, wc.z, a0.z); a0.w = fmaf(e0.z, wc.w, a0.w);
        a0.x = fmaf(e0.w, wd.x, a0.x); a0.y = fmaf(e0.w, wd.y, a0.y);
        a0.z = fmaf(e0.w, wd.z, a0.z); a0.w = fmaf(e0.w, wd.w, a0.w);
    }
    if (half) {
        float4 bb = *(const float4*)(b1 + c);
        a0.x += bb.x; a0.y += bb.y; a0.z += bb.z; a0.w += bb.w;
    }
    *(float4*)(W + ((half << 9) + r0 + rp) * D_ + c) = a0;
}

// ---------------- K2: fused stats -> cov -> rstd -> gelu-dot -> sigmoid ----
// 528 blocks = upper-triangle 16x16 pair tiles. 512 thr (8 waves) = 32 pair-
// threads (pt: 2x4 pair block) x 16 k-slices (ks, low 4 lane bits). Full
// 16x512 raw l/r tiles resident in LDS (66KB -> 2 blocks/CU, 16 waves/CU).
// launch_bounds(512,2): CUDA semantics = min 2 BLOCKS/CU -> 128-VGPR cap.
// ((512,4) capped VGPRs at 64 -> spill: WRITE_SIZE 43MB, the round-1/2 bug.)

// gelu_tanh(x) = x * sigmoid(1.5957691*(x + 0.044715 x^3))
// q = log2(exp(-2y)) = x*(A*x^2+B), B = -2*log2e*0.79788456, A = B*0.044715
// x = ((l+r) - mm)*rst*g + be = fmaf(fmaf(s, RST, T2N), g, be), T2N = -mm*rst
#define GELU1(L, R, G, BE, WC, RST, T2N, ACC)                                 \
    do {                                                                      \
        float s_ = (L) + (R);                                                 \
        float x_ = fmaf(fmaf(s_, (RST), (T2N)), (G), (BE));                   \
        float q_ = x_ * fmaf(-0.10294340f, x_ * x_, -2.30220935f);            \
        float e_ = __builtin_amdgcn_exp2f(q_);                                \
        float ge_ = x_ * __builtin_amdgcn_rcpf(1.f + e_);                     \
        ACC = fmaf(ge_, (WC), ACC);                                           \
    } while (0)

#define GELU4(LQ, RQ, RST, T2N, ACC)                                          \
    do {                                                                      \
        GELU1(LQ.x, RQ.x, g4.x, be4.x, w4.x, RST, T2N, ACC);                  \
        GELU1(LQ.y, RQ.y, g4.y, be4.y, w4.y, RST, T2N, ACC);                  \
        GELU1(LQ.z, RQ.z, g4.z, be4.z, w4.z, RST, T2N, ACC);                  \
        GELU1(LQ.w, RQ.w, g4.w, be4.w, w4.w, RST, T2N, ACC);                  \
    } while (0)

#define DOT4(LQ, RQ, ACC)                                                     \
    ACC += LQ.x * RQ.x + LQ.y * RQ.y + LQ.z * RQ.z + LQ.w * RQ.w

#define BFLY(V)                                                               \
    do {                                                                      \
        V += __shfl_xor(V, 1, 64);                                            \
        V += __shfl_xor(V, 2, 64);                                            \
        V += __shfl_xor(V, 4, 64);                                            \
        V += __shfl_xor(V, 8, 64);                                            \
    } while (0)

__global__ __launch_bounds__(512, 2) void k_pair(const float* __restrict__ W,
                                                 const float* __restrict__ gf,
                                                 const float* __restrict__ bef,
                                                 const float* __restrict__ wf,
                                                 const float* __restrict__ b2f,
                                                 float* __restrict__ out) {
    __shared__ float ls[16][516];   // 516 mod 32 = 4 -> reads spread 8 bank-quads
    __shared__ float rs[16][516];
    __shared__ float smean[32];     // rows 0-15: ls, 16-31: rs
    __shared__ float svar[32];

    // decode upper-triangle tile index b -> (I, J), I<=J, 32 tile-rows
    const int b = blockIdx.x;
    int I = (int)((65.0f - sqrtf(4225.0f - 8.0f * (float)b)) * 0.5f);
    if (I < 0) I = 0;
    if (I > 31) I = 31;
#define S_(i) (32 * (i) - ((i) * ((i)-1)) / 2)
    while (S_(I) > b) --I;
    while (S_(I + 1) <= b) ++I;
    const int J = I + (b - S_(I));
#undef S_

    const int t = threadIdx.x;
    const int ks = t & 15;          // k-slice: lane bits 0..3 -> shfl-reducible
    const int pt = t >> 4;          // 0..31 pair-threads
    const int i2 = (pt & 7) * 2, j4 = (pt >> 3) * 4;
    const int Ibase = I * 16, Jbase = N_ + J * 16;

    // ---- stage full raw tiles once (coalesced 1KB/row chunks) ----
    for (int x = t; x < 16 * 128; x += 512) {
        int r = x >> 7, c4 = (x & 127) << 2;
        *(float4*)&ls[r][c4] = *(const float4*)&W[(Ibase + r) * D_ + c4];
        *(float4*)&rs[r][c4] = *(const float4*)&W[(Jbase + r) * D_ + c4];
    }
    __syncthreads();

    // ---- per-row mean/var from resident tiles (wave-parallel, 4 rows/wave) --
    {
        const int lane = t & 63, w = t >> 6;
#pragma unroll
        for (int rr = 0; rr < 4; ++rr) {
            const int row = w * 4 + rr;                 // 0..31
            const float* p = (row < 16) ? &ls[row][0] : &rs[row - 16][0];
            float4 a = *(const float4*)&p[lane << 2];
            float4 c = *(const float4*)&p[256 + (lane << 2)];
            float sm = (a.x + a.y) + (a.z + a.w) + (c.x + c.y) + (c.z + c.w);
            float sq = a.x * a.x + a.y * a.y + a.z * a.z + a.w * a.w +
                       c.x * c.x + c.y * c.y + c.z * c.z + c.w * c.w;
#pragma unroll
            for (int off = 32; off > 0; off >>= 1) {
                sm += __shfl_xor(sm, off, 64);
                sq += __shfl_xor(sq, off, 64);
            }
            if (lane == 0) {
                float mu = sm * (1.f / D_);
                smean[row] = mu;
                svar[row] = fmaf(-mu, mu, sq * (1.f / D_));
            }
        }
    }
    __syncthreads();

    // ---- pass A: raw cov-dot (2 l-rows x 4 r-rows, named scalar chains) ----
    float cv0 = 0.f, cv1 = 0.f, cv2 = 0.f, cv3 = 0.f;
    float cv4 = 0.f, cv5 = 0.f, cv6 = 0.f, cv7 = 0.f;
    for (int it = 0; it < 8; ++it) {
        const int kq = (it * 16 + ks) * 4;
        float4 la = *(float4*)&ls[i2][kq];
        float4 lb = *(float4*)&ls[i2 + 1][kq];
        float4 ra = *(float4*)&rs[j4][kq];
        float4 rb = *(float4*)&rs[j4 + 1][kq];
        float4 rc = *(float4*)&rs[j4 + 2][kq];
        float4 rd = *(float4*)&rs[j4 + 3][kq];
        DOT4(la, ra, cv0); DOT4(la, rb, cv1); DOT4(la, rc, cv2); DOT4(la, rd, cv3);
        DOT4(lb, ra, cv4); DOT4(lb, rb, cv5); DOT4(lb, rc, cv6); DOT4(lb, rd, cv7);
    }
    BFLY(cv0); BFLY(cv1); BFLY(cv2); BFLY(cv3);
    BFLY(cv4); BFLY(cv5); BFLY(cv6); BFLY(cv7);

    // ---- rstd + mean-shift in-register ----
    // varh = var_l + var_r + cv*(2/D) - 2*ml*mr + eps ; t2n = -(ml+mr)*rst
    const float ml0 = smean[i2], ml1 = smean[i2 + 1];
    const float vl0 = svar[i2], vl1 = svar[i2 + 1];
    const float mr0 = smean[16 + j4],     mr1 = smean[16 + j4 + 1];
    const float mr2 = smean[16 + j4 + 2], mr3 = smean[16 + j4 + 3];
    const float vr0 = svar[16 + j4],     vr1 = svar[16 + j4 + 1];
    const float vr2 = svar[16 + j4 + 2], vr3 = svar[16 + j4 + 3];
    const float rst0 = rsqrtf(vl0 + vr0 + cv0 * (2.f / D_) - 2.f * ml0 * mr0 + 1e-5f);
    const float rst1 = rsqrtf(vl0 + vr1 + cv1 * (2.f / D_) - 2.f * ml0 * mr1 + 1e-5f);
    const float rst2 = rsqrtf(vl0 + vr2 + cv2 * (2.f / D_) - 2.f * ml0 * mr2 + 1e-5f);
    const float rst3 = rsqrtf(vl0 + vr3 + cv3 * (2.f / D_) - 2.f * ml0 * mr3 + 1e-5f);
    const float rst4 = rsqrtf(vl1 + vr0 + cv4 * (2.f / D_) - 2.f * ml1 * mr0 + 1e-5f);
    const float rst5 = rsqrtf(vl1 + vr1 + cv5 * (2.f / D_) - 2.f * ml1 * mr1 + 1e-5f);
    const float rst6 = rsqrtf(vl1 + vr2 + cv6 * (2.f / D_) - 2.f * ml1 * mr2 + 1e-5f);
    const float rst7 = rsqrtf(vl1 + vr3 + cv7 * (2.f / D_) - 2.f * ml1 * mr3 + 1e-5f);
    const float t2n0 = -(ml0 + mr0) * rst0;
    const float t2n1 = -(ml0 + mr1) * rst1;
    const float t2n2 = -(ml0 + mr2) * rst2;
    const float t2n3 = -(ml0 + mr3) * rst3;
    const float t2n4 = -(ml1 + mr0) * rst4;
    const float t2n5 = -(ml1 + mr1) * rst5;
    const float t2n6 = -(ml1 + mr2) * rst6;
    const float t2n7 = -(ml1 + mr3) * rst7;

    // ---- pass B: gelu dot over the same resident tiles ----
    float ac0 = 0.f, ac1 = 0.f, ac2 = 0.f, ac3 = 0.f;
    float ac4 = 0.f, ac5 = 0.f, ac6 = 0.f, ac7 = 0.f;
    for (int it = 0; it < 8; ++it) {
        const int kq = (it * 16 + ks) * 4;
        float4 g4 = *(const float4*)&gf[kq];
        float4 be4 = *(const float4*)&bef[kq];
        float4 w4 = *(const float4*)&wf[kq];
        float4 la = *(float4*)&ls[i2][kq];
        float4 lb = *(float4*)&ls[i2 + 1][kq];
        float4 ra = *(float4*)&rs[j4][kq];
        float4 rb = *(float4*)&rs[j4 + 1][kq];
        float4 rc = *(float4*)&rs[j4 + 2][kq];
        float4 rd = *(float4*)&rs[j4 + 3][kq];
        GELU4(la, ra, rst0, t2n0, ac0); GELU4(la, rb, rst1, t2n1, ac1);
        GELU4(la, rc, rst2, t2n2, ac2); GELU4(la, rd, rst3, t2n3, ac3);
        GELU4(lb, ra, rst4, t2n4, ac4); GELU4(lb, rb, rst5, t2n5, ac5);
        GELU4(lb, rc, rst6, t2n6, ac6); GELU4(lb, rd, rst7, t2n7, ac7);
    }
    BFLY(ac0); BFLY(ac1); BFLY(ac2); BFLY(ac3);
    BFLY(ac4); BFLY(ac5); BFLY(ac6); BFLY(ac7);

    // ---- sigmoid + mirrored store (ks==0 lane of each pair-thread) ----
    if (ks == 0) {
        const float bb = b2f[0];
        const float z0 = __builtin_amdgcn_rcpf(
            1.f + __builtin_amdgcn_exp2f(-1.44269504f * (ac0 + bb)));
        const float z1 = __builtin_amdgcn_rcpf(
            1.f + __builtin_amdgcn_exp2f(-1.44269504f * (ac1 + bb)));
        const float z2 = __builtin_amdgcn_rcpf(
            1.f + __builtin_amdgcn_exp2f(-1.44269504f * (ac2 + bb)));
        const float z3 = __builtin_amdgcn_rcpf(
            1.f + __builtin_amdgcn_exp2f(-1.44269504f * (ac3 + bb)));
        const float z4 = __builtin_amdgcn_rcpf(
            1.f + __builtin_amdgcn_exp2f(-1.44269504f * (ac4 + bb)));
        const float z5 = __builtin_amdgcn_rcpf(
            1.f + __builtin_amdgcn_exp2f(-1.44269504f * (ac5 + bb)));
        const float z6 = __builtin_amdgcn_rcpf(
            1.f + __builtin_amdgcn_exp2f(-1.44269504f * (ac6 + bb)));
        const float z7 = __builtin_amdgcn_rcpf(
            1.f + __builtin_amdgcn_exp2f(-1.44269504f * (ac7 + bb)));
        const int gi0 = Ibase + i2;
        const int gj0 = (Jbase - N_) + j4;
        if (I < J) {
            float4 o0 = {z0, z1, z2, z3};
            float4 o1 = {z4, z5, z6, z7};
            *(float4*)&out[gi0 * N_ + gj0] = o0;
            *(float4*)&out[(gi0 + 1) * N_ + gj0] = o1;
            out[gj0 * N_ + gi0] = z0;       out[gj0 * N_ + gi0 + 1] = z4;
            out[(gj0 + 1) * N_ + gi0] = z1; out[(gj0 + 1) * N_ + gi0 + 1] = z5;
            out[(gj0 + 2) * N_ + gi0] = z2; out[(gj0 + 2) * N_ + gi0 + 1] = z6;
            out[(gj0 + 3) * N_ + gi0] = z3; out[(gj0 + 3) * N_ + gi0 + 1] = z7;
        } else {  // diagonal tile: only pairs gi<=gj are valid
            if (gi0 <= gj0)     { out[gi0 * N_ + gj0] = z0;       out[gj0 * N_ + gi0] = z0; }
            if (gi0 <= gj0 + 1) { out[gi0 * N_ + gj0 + 1] = z1;   out[(gj0 + 1) * N_ + gi0] = z1; }
            if (gi0 <= gj0 + 2) { out[gi0 * N_ + gj0 + 2] = z2;   out[(gj0 + 2) * N_ + gi0] = z2; }
            if (gi0 <= gj0 + 3) { out[gi0 * N_ + gj0 + 3] = z3;   out[(gj0 + 3) * N_ + gi0] = z3; }
            if (gi0 + 1 <= gj0)     { out[(gi0 + 1) * N_ + gj0] = z4;     out[gj0 * N_ + gi0 + 1] = z4; }
            if (gi0 + 1 <= gj0 + 1) { out[(gi0 + 1) * N_ + gj0 + 1] = z5; out[(gj0 + 1) * N_ + gi0 + 1] = z5; }
            if (gi0 + 1 <= gj0 + 2) { out[(gi0 + 1) * N_ + gj0 + 2] = z6; out[(gj0 + 2) * N_ + gi0 + 1] = z6; }
            if (gi0 + 1 <= gj0 + 3) { out[(gi0 + 1) * N_ + gj0 + 3] = z7; out[(gj0 + 3) * N_ + gi0 + 1] = z7; }
        }
    }
}

extern "C" void kernel_launch(void* const* d_in, const int* in_sizes, int n_in,
                              void* d_out, int out_size, void* d_ws, size_t ws_size,
                              hipStream_t stream) {
    const float* E     = (const float*)d_in[0];
    const float* W1    = (const float*)d_in[1];
    const float* b1    = (const float*)d_in[2];
    const float* gamma = (const float*)d_in[3];
    const float* beta  = (const float*)d_in[4];
    const float* w2    = (const float*)d_in[5];
    const float* b2    = (const float*)d_in[6];
    float* out = (float*)d_out;

    float* lcrc = (float*)d_ws;       // [1024][512]: rows 0..511 lc, 512..1023 rc(+b1)

    k_gemm<<<256, 512, 0, stream>>>(E, W1, b1, lcrc);
    k_pair<<<528, 512, 0, stream>>>(lcrc, gamma, beta, w2, b2, out);
}

// Round 4
// 123.199 us; speedup vs baseline: 1.2012x; 1.2012x over previous
//
#include <hip/hip_runtime.h>

// N=512, D=512 pairwise scorer, all f32.
// left = E@W1[:D]; right = E@W1[D:]+b1; h = left[i]+right[j]; LN(D); GELU; @W2+b2; sigmoid.
// LN stats decompose over RAW (uncentered) rows:
//   var_h = var_l[i] + var_r[j] + 2*(dot_raw(i,j)/D - ml[i]*mr[j])
//   x_k   = ((l_k + r_k) - ml - mr) * rstd * g_k + be_k
// Two kernels. Never materialize [N,N,D].

#define N_ 512
#define D_ 512

// ---------------- K1: left/right GEMMs ----------------
// Round-3 post-mortem: old shape (4 outputs/thread, full-K) = only 2048 waves
// total = 8 waves/CU in one round -> duration = single-wave latency (VALUBusy
// 9%, 50us). New shape: block = 16 rows x 64 cols, K SPLIT 8-ways in-block
// (wave = 64-k slice). 512 blocks x 8 waves = 4096 waves = 16 waves/CU.
// E tile staged TRANSPOSED in LDS (et[k][r], stride 20: b128-aligned,
// conflict-free). Per k: 1 global dwordx4 (W1) + 1 ds_read_b128 (4 e-rows) +
// 16 FMA (4 rows x 4 cols in regs). W1 read ONCE per block. Partials reduced
// via LDS overlay on et.
__global__ __launch_bounds__(512, 2) void k_gemm(const float* __restrict__ E,
                                                 const float* __restrict__ W1,
                                                 const float* __restrict__ b1,
                                                 float* __restrict__ W /* [1024][512] */) {
    __shared__ float et[512 * 20];  // et[k][r]: addr k*20+r. 40KB. Overlaid by red[8][1024].

    const int t = threadIdx.x;
    const int bg = blockIdx.x;
    const int rg = bg >> 4;                 // 0..31 row group
    const int cg = bg & 15;                 // 0..15 col group (64 combined cols)
    const int r0 = rg * 16;
    const int half = cg >> 3;               // 0: left, 1: right(+b1)
    const int cb = (cg & 7) << 6;           // col base within half (0..448)

    // ---- stage E[r0..r0+15][0..511] transposed: et[k*20 + r] ----
    for (int x = t; x < 16 * 128; x += 512) {
        const int r = x >> 7, k4 = (x & 127) << 2;
        float4 v = *(const float4*)&E[(r0 + r) * D_ + k4];
        et[(k4 + 0) * 20 + r] = v.x;
        et[(k4 + 1) * 20 + r] = v.y;
        et[(k4 + 2) * 20 + r] = v.z;
        et[(k4 + 3) * 20 + r] = v.w;
    }
    __syncthreads();

    // ---- main: wave = k-slice (64 k), lane = 16 col-quads x 4 row-quads ----
    const int lane = t & 63;
    const int ks = t >> 6;                  // 0..7
    const int kb = ks << 6;
    const int c4 = (lane & 15) << 2;        // 0..60
    const int rq = ((lane >> 4) & 3) << 2;  // 0,4,8,12
    const float* __restrict__ wp = W1 + (half << 18) + (kb << 9) + cb + c4;

    float4 a0 = {0.f, 0.f, 0.f, 0.f}, a1 = {0.f, 0.f, 0.f, 0.f};
    float4 a2 = {0.f, 0.f, 0.f, 0.f}, a3 = {0.f, 0.f, 0.f, 0.f};
#pragma unroll 4
    for (int k = 0; k < 64; ++k) {
        float4 wv = *(const float4*)(wp + (k << 9));
        float4 ev = *(const float4*)&et[(kb + k) * 20 + rq];
        a0.x = fmaf(ev.x, wv.x, a0.x); a0.y = fmaf(ev.x, wv.y, a0.y);
        a0.z = fmaf(ev.x, wv.z, a0.z); a0.w = fmaf(ev.x, wv.w, a0.w);
        a1.x = fmaf(ev.y, wv.x, a1.x); a1.y = fmaf(ev.y, wv.y, a1.y);
        a1.z = fmaf(ev.y, wv.z, a1.z); a1.w = fmaf(ev.y, wv.w, a1.w);
        a2.x = fmaf(ev.z, wv.x, a2.x); a2.y = fmaf(ev.z, wv.y, a2.y);
        a2.z = fmaf(ev.z, wv.z, a2.z); a2.w = fmaf(ev.z, wv.w, a2.w);
        a3.x = fmaf(ev.w, wv.x, a3.x); a3.y = fmaf(ev.w, wv.y, a3.y);
        a3.z = fmaf(ev.w, wv.z, a3.z); a3.w = fmaf(ev.w, wv.w, a3.w);
    }

    // ---- reduce the 8 k-slice partials via LDS overlay on et ----
    __syncthreads();                         // all et reads done
    float* red = et;                         // red[ks][1024], 32KB
    const int ob = (ks << 10) + c4;
    *(float4*)&red[ob + ((rq + 0) << 6)] = a0;
    *(float4*)&red[ob + ((rq + 1) << 6)] = a1;
    *(float4*)&red[ob + ((rq + 2) << 6)] = a2;
    *(float4*)&red[ob + ((rq + 3) << 6)] = a3;
    __syncthreads();

    // thread t -> outputs 2t, 2t+1 (row t>>5, cols (2t)&63)
    float2 s = {0.f, 0.f};
#pragma unroll
    for (int k2 = 0; k2 < 8; ++k2) {
        float2 p = *(const float2*)&red[(k2 << 10) + (t << 1)];
        s.x += p.x; s.y += p.y;
    }
    const int ro = t >> 5, co = (t << 1) & 63;
    if (half) {
        float2 bb = *(const float2*)&b1[cb + co];
        s.x += bb.x; s.y += bb.y;
    }
    *(float2*)&W[((half << 9) + r0 + ro) * D_ + cb + co] = s;
}

// ---------------- K2: fused stats -> cov -> rstd -> gelu-dot -> sigmoid ----
// 528 blocks = upper-triangle 16x16 pair tiles. 512 thr (8 waves) = 32 pair-
// threads (pt: 2x4 pair block) x 16 k-slices (ks, low 4 lane bits). Full
// 16x512 raw l/r tiles resident in LDS (66KB -> 2 blocks/CU, 16 waves/CU).
// launch_bounds(512,2): CUDA semantics = min 2 BLOCKS/CU -> 128-VGPR cap.
// ((512,4) capped VGPRs at 64 -> spill: WRITE_SIZE 43MB, the round-1/2 bug.)

// gelu_tanh(x) = x * sigmoid(1.5957691*(x + 0.044715 x^3))
// q = log2(exp(-2y)) = x*(A*x^2+B), B = -2*log2e*0.79788456, A = B*0.044715
// x = ((l+r) - mm)*rst*g + be = fmaf(fmaf(s, RST, T2N), g, be), T2N = -mm*rst
#define GELU1(L, R, G, BE, WC, RST, T2N, ACC)                                 \
    do {                                                                      \
        float s_ = (L) + (R);                                                 \
        float x_ = fmaf(fmaf(s_, (RST), (T2N)), (G), (BE));                   \
        float q_ = x_ * fmaf(-0.10294340f, x_ * x_, -2.30220935f);            \
        float e_ = __builtin_amdgcn_exp2f(q_);                                \
        float ge_ = x_ * __builtin_amdgcn_rcpf(1.f + e_);                     \
        ACC = fmaf(ge_, (WC), ACC);                                           \
    } while (0)

#define GELU4(LQ, RQ, RST, T2N, ACC)                                          \
    do {                                                                      \
        GELU1(LQ.x, RQ.x, g4.x, be4.x, w4.x, RST, T2N, ACC);                  \
        GELU1(LQ.y, RQ.y, g4.y, be4.y, w4.y, RST, T2N, ACC);                  \
        GELU1(LQ.z, RQ.z, g4.z, be4.z, w4.z, RST, T2N, ACC);                  \
        GELU1(LQ.w, RQ.w, g4.w, be4.w, w4.w, RST, T2N, ACC);                  \
    } while (0)

#define DOT4(LQ, RQ, ACC)                                                     \
    ACC += LQ.x * RQ.x + LQ.y * RQ.y + LQ.z * RQ.z + LQ.w * RQ.w

#define BFLY(V)                                                               \
    do {                                                                      \
        V += __shfl_xor(V, 1, 64);                                            \
        V += __shfl_xor(V, 2, 64);                                            \
        V += __shfl_xor(V, 4, 64);                                            \
        V += __shfl_xor(V, 8, 64);                                            \
    } while (0)

__global__ __launch_bounds__(512, 2) void k_pair(const float* __restrict__ W,
                                                 const float* __restrict__ gf,
                                                 const float* __restrict__ bef,
                                                 const float* __restrict__ wf,
                                                 const float* __restrict__ b2f,
                                                 float* __restrict__ out) {
    __shared__ float ls[16][516];   // 516 mod 32 = 4 -> reads spread 8 bank-quads
    __shared__ float rs[16][516];
    __shared__ float smean[32];     // rows 0-15: ls, 16-31: rs
    __shared__ float svar[32];

    // decode upper-triangle tile index b -> (I, J), I<=J, 32 tile-rows
    const int b = blockIdx.x;
    int I = (int)((65.0f - sqrtf(4225.0f - 8.0f * (float)b)) * 0.5f);
    if (I < 0) I = 0;
    if (I > 31) I = 31;
#define S_(i) (32 * (i) - ((i) * ((i)-1)) / 2)
    while (S_(I) > b) --I;
    while (S_(I + 1) <= b) ++I;
    const int J = I + (b - S_(I));
#undef S_

    const int t = threadIdx.x;
    const int ks = t & 15;          // k-slice: lane bits 0..3 -> shfl-reducible
    const int pt = t >> 4;          // 0..31 pair-threads
    const int i2 = (pt & 7) * 2, j4 = (pt >> 3) * 4;
    const int Ibase = I * 16, Jbase = N_ + J * 16;

    // ---- stage full raw tiles once (coalesced 1KB/row chunks) ----
    for (int x = t; x < 16 * 128; x += 512) {
        int r = x >> 7, c4 = (x & 127) << 2;
        *(float4*)&ls[r][c4] = *(const float4*)&W[(Ibase + r) * D_ + c4];
        *(float4*)&rs[r][c4] = *(const float4*)&W[(Jbase + r) * D_ + c4];
    }
    __syncthreads();

    // ---- per-row mean/var from resident tiles (wave-parallel, 4 rows/wave) --
    {
        const int lane = t & 63, w = t >> 6;
#pragma unroll
        for (int rr = 0; rr < 4; ++rr) {
            const int row = w * 4 + rr;                 // 0..31
            const float* p = (row < 16) ? &ls[row][0] : &rs[row - 16][0];
            float4 a = *(const float4*)&p[lane << 2];
            float4 c = *(const float4*)&p[256 + (lane << 2)];
            float sm = (a.x + a.y) + (a.z + a.w) + (c.x + c.y) + (c.z + c.w);
            float sq = a.x * a.x + a.y * a.y + a.z * a.z + a.w * a.w +
                       c.x * c.x + c.y * c.y + c.z * c.z + c.w * c.w;
#pragma unroll
            for (int off = 32; off > 0; off >>= 1) {
                sm += __shfl_xor(sm, off, 64);
                sq += __shfl_xor(sq, off, 64);
            }
            if (lane == 0) {
                float mu = sm * (1.f / D_);
                smean[row] = mu;
                svar[row] = fmaf(-mu, mu, sq * (1.f / D_));
            }
        }
    }
    __syncthreads();

    // ---- pass A: raw cov-dot (2 l-rows x 4 r-rows, named scalar chains) ----
    float cv0 = 0.f, cv1 = 0.f, cv2 = 0.f, cv3 = 0.f;
    float cv4 = 0.f, cv5 = 0.f, cv6 = 0.f, cv7 = 0.f;
    for (int it = 0; it < 8; ++it) {
        const int kq = (it * 16 + ks) * 4;
        float4 la = *(float4*)&ls[i2][kq];
        float4 lb = *(float4*)&ls[i2 + 1][kq];
        float4 ra = *(float4*)&rs[j4][kq];
        float4 rb = *(float4*)&rs[j4 + 1][kq];
        float4 rc = *(float4*)&rs[j4 + 2][kq];
        float4 rd = *(float4*)&rs[j4 + 3][kq];
        DOT4(la, ra, cv0); DOT4(la, rb, cv1); DOT4(la, rc, cv2); DOT4(la, rd, cv3);
        DOT4(lb, ra, cv4); DOT4(lb, rb, cv5); DOT4(lb, rc, cv6); DOT4(lb, rd, cv7);
    }
    BFLY(cv0); BFLY(cv1); BFLY(cv2); BFLY(cv3);
    BFLY(cv4); BFLY(cv5); BFLY(cv6); BFLY(cv7);

    // ---- rstd + mean-shift in-register ----
    // varh = var_l + var_r + cv*(2/D) - 2*ml*mr + eps ; t2n = -(ml+mr)*rst
    const float ml0 = smean[i2], ml1 = smean[i2 + 1];
    const float vl0 = svar[i2], vl1 = svar[i2 + 1];
    const float mr0 = smean[16 + j4],     mr1 = smean[16 + j4 + 1];
    const float mr2 = smean[16 + j4 + 2], mr3 = smean[16 + j4 + 3];
    const float vr0 = svar[16 + j4],     vr1 = svar[16 + j4 + 1];
    const float vr2 = svar[16 + j4 + 2], vr3 = svar[16 + j4 + 3];
    const float rst0 = rsqrtf(vl0 + vr0 + cv0 * (2.f / D_) - 2.f * ml0 * mr0 + 1e-5f);
    const float rst1 = rsqrtf(vl0 + vr1 + cv1 * (2.f / D_) - 2.f * ml0 * mr1 + 1e-5f);
    const float rst2 = rsqrtf(vl0 + vr2 + cv2 * (2.f / D_) - 2.f * ml0 * mr2 + 1e-5f);
    const float rst3 = rsqrtf(vl0 + vr3 + cv3 * (2.f / D_) - 2.f * ml0 * mr3 + 1e-5f);
    const float rst4 = rsqrtf(vl1 + vr0 + cv4 * (2.f / D_) - 2.f * ml1 * mr0 + 1e-5f);
    const float rst5 = rsqrtf(vl1 + vr1 + cv5 * (2.f / D_) - 2.f * ml1 * mr1 + 1e-5f);
    const float rst6 = rsqrtf(vl1 + vr2 + cv6 * (2.f / D_) - 2.f * ml1 * mr2 + 1e-5f);
    const float rst7 = rsqrtf(vl1 + vr3 + cv7 * (2.f / D_) - 2.f * ml1 * mr3 + 1e-5f);
    const float t2n0 = -(ml0 + mr0) * rst0;
    const float t2n1 = -(ml0 + mr1) * rst1;
    const float t2n2 = -(ml0 + mr2) * rst2;
    const float t2n3 = -(ml0 + mr3) * rst3;
    const float t2n4 = -(ml1 + mr0) * rst4;
    const float t2n5 = -(ml1 + mr1) * rst5;
    const float t2n6 = -(ml1 + mr2) * rst6;
    const float t2n7 = -(ml1 + mr3) * rst7;

    // ---- pass B: gelu dot over the same resident tiles ----
    float ac0 = 0.f, ac1 = 0.f, ac2 = 0.f, ac3 = 0.f;
    float ac4 = 0.f, ac5 = 0.f, ac6 = 0.f, ac7 = 0.f;
    for (int it = 0; it < 8; ++it) {
        const int kq = (it * 16 + ks) * 4;
        float4 g4 = *(const float4*)&gf[kq];
        float4 be4 = *(const float4*)&bef[kq];
        float4 w4 = *(const float4*)&wf[kq];
        float4 la = *(float4*)&ls[i2][kq];
        float4 lb = *(float4*)&ls[i2 + 1][kq];
        float4 ra = *(float4*)&rs[j4][kq];
        float4 rb = *(float4*)&rs[j4 + 1][kq];
        float4 rc = *(float4*)&rs[j4 + 2][kq];
        float4 rd = *(float4*)&rs[j4 + 3][kq];
        GELU4(la, ra, rst0, t2n0, ac0); GELU4(la, rb, rst1, t2n1, ac1);
        GELU4(la, rc, rst2, t2n2, ac2); GELU4(la, rd, rst3, t2n3, ac3);
        GELU4(lb, ra, rst4, t2n4, ac4); GELU4(lb, rb, rst5, t2n5, ac5);
        GELU4(lb, rc, rst6, t2n6, ac6); GELU4(lb, rd, rst7, t2n7, ac7);
    }
    BFLY(ac0); BFLY(ac1); BFLY(ac2); BFLY(ac3);
    BFLY(ac4); BFLY(ac5); BFLY(ac6); BFLY(ac7);

    // ---- sigmoid + mirrored store (ks==0 lane of each pair-thread) ----
    if (ks == 0) {
        const float bb = b2f[0];
        const float z0 = __builtin_amdgcn_rcpf(
            1.f + __builtin_amdgcn_exp2f(-1.44269504f * (ac0 + bb)));
        const float z1 = __builtin_amdgcn_rcpf(
            1.f + __builtin_amdgcn_exp2f(-1.44269504f * (ac1 + bb)));
        const float z2 = __builtin_amdgcn_rcpf(
            1.f + __builtin_amdgcn_exp2f(-1.44269504f * (ac2 + bb)));
        const float z3 = __builtin_amdgcn_rcpf(
            1.f + __builtin_amdgcn_exp2f(-1.44269504f * (ac3 + bb)));
        const float z4 = __builtin_amdgcn_rcpf(
            1.f + __builtin_amdgcn_exp2f(-1.44269504f * (ac4 + bb)));
        const float z5 = __builtin_amdgcn_rcpf(
            1.f + __builtin_amdgcn_exp2f(-1.44269504f * (ac5 + bb)));
        const float z6 = __builtin_amdgcn_rcpf(
            1.f + __builtin_amdgcn_exp2f(-1.44269504f * (ac6 + bb)));
        const float z7 = __builtin_amdgcn_rcpf(
            1.f + __builtin_amdgcn_exp2f(-1.44269504f * (ac7 + bb)));
        const int gi0 = Ibase + i2;
        const int gj0 = (Jbase - N_) + j4;
        if (I < J) {
            float4 o0 = {z0, z1, z2, z3};
            float4 o1 = {z4, z5, z6, z7};
            *(float4*)&out[gi0 * N_ + gj0] = o0;
            *(float4*)&out[(gi0 + 1) * N_ + gj0] = o1;
            out[gj0 * N_ + gi0] = z0;       out[gj0 * N_ + gi0 + 1] = z4;
            out[(gj0 + 1) * N_ + gi0] = z1; out[(gj0 + 1) * N_ + gi0 + 1] = z5;
            out[(gj0 + 2) * N_ + gi0] = z2; out[(gj0 + 2) * N_ + gi0 + 1] = z6;
            out[(gj0 + 3) * N_ + gi0] = z3; out[(gj0 + 3) * N_ + gi0 + 1] = z7;
        } else {  // diagonal tile: only pairs gi<=gj are valid
            if (gi0 <= gj0)     { out[gi0 * N_ + gj0] = z0;       out[gj0 * N_ + gi0] = z0; }
            if (gi0 <= gj0 + 1) { out[gi0 * N_ + gj0 + 1] = z1;   out[(gj0 + 1) * N_ + gi0] = z1; }
            if (gi0 <= gj0 + 2) { out[gi0 * N_ + gj0 + 2] = z2;   out[(gj0 + 2) * N_ + gi0] = z2; }
            if (gi0 <= gj0 + 3) { out[gi0 * N_ + gj0 + 3] = z3;   out[(gj0 + 3) * N_ + gi0] = z3; }
            if (gi0 + 1 <= gj0)     { out[(gi0 + 1) * N_ + gj0] = z4;     out[gj0 * N_ + gi0 + 1] = z4; }
            if (gi0 + 1 <= gj0 + 1) { out[(gi0 + 1) * N_ + gj0 + 1] = z5; out[(gj0 + 1) * N_ + gi0 + 1] = z5; }
            if (gi0 + 1 <= gj0 + 2) { out[(gi0 + 1) * N_ + gj0 + 2] = z6; out[(gj0 + 2) * N_ + gi0 + 1] = z6; }
            if (gi0 + 1 <= gj0 + 3) { out[(gi0 + 1) * N_ + gj0 + 3] = z7; out[(gj0 + 3) * N_ + gi0 + 1] = z7; }
        }
    }
}

extern "C" void kernel_launch(void* const* d_in, const int* in_sizes, int n_in,
                              void* d_out, int out_size, void* d_ws, size_t ws_size,
                              hipStream_t stream) {
    const float* E     = (const float*)d_in[0];
    const float* W1    = (const float*)d_in[1];
    const float* b1    = (const float*)d_in[2];
    const float* gamma = (const float*)d_in[3];
    const float* beta  = (const float*)d_in[4];
    const float* w2    = (const float*)d_in[5];
    const float* b2    = (const float*)d_in[6];
    float* out = (float*)d_out;

    float* lcrc = (float*)d_ws;       // [1024][512]: rows 0..511 lc, 512..1023 rc(+b1)

    k_gemm<<<512, 512, 0, stream>>>(E, W1, b1, lcrc);
    k_pair<<<528, 512, 0, stream>>>(lcrc, gamma, beta, w2, b2, out);
}

// Round 5
// 115.649 us; speedup vs baseline: 1.2797x; 1.0653x over previous
//
#include <hip/hip_runtime.h>

// N=512, D=512 pairwise scorer, all f32.
// left = E@W1[:D]; right = E@W1[D:]+b1; h = left[i]+right[j]; LN(D); GELU; @W2+b2; sigmoid.
// LN stats decompose over RAW (uncentered) rows:
//   var_h = var_l[i] + var_r[j] + 2*(dot_raw(i,j)/D - ml[i]*mr[j])
//   x_k   = ((l_k + r_k) - ml - mr) * rstd * g_k + be_k
// Two kernels. Never materialize [N,N,D].

#define N_ 512
#define D_ 512

// ---------------- K1: left/right GEMMs ----------------
// Block = 16 rows x 64 combined cols, K split 8-ways in-block (wave = 64-k
// slice). 512 blocks x 8 waves = 16 waves/CU. E tile staged TRANSPOSED in LDS
// (et[k][r], stride 20). Per k: 1 global dwordx4 (W1) + 1 ds_read_b128 +
// 16 FMA. W1 read once per block. Partials reduced via LDS overlay on et.
// unroll 8: 8 W1 loads in flight to cover L2 latency.
__global__ __launch_bounds__(512, 2) void k_gemm(const float* __restrict__ E,
                                                 const float* __restrict__ W1,
                                                 const float* __restrict__ b1,
                                                 float* __restrict__ W /* [1024][512] */) {
    __shared__ float et[512 * 20];  // et[k][r]: addr k*20+r. 40KB. Overlaid by red[8][1024].

    const int t = threadIdx.x;
    const int bg = blockIdx.x;
    const int rg = bg >> 4;                 // 0..31 row group
    const int cg = bg & 15;                 // 0..15 col group (64 combined cols)
    const int r0 = rg * 16;
    const int half = cg >> 3;               // 0: left, 1: right(+b1)
    const int cb = (cg & 7) << 6;           // col base within half (0..448)

    // ---- stage E[r0..r0+15][0..511] transposed: et[k*20 + r] ----
    for (int x = t; x < 16 * 128; x += 512) {
        const int r = x >> 7, k4 = (x & 127) << 2;
        float4 v = *(const float4*)&E[(r0 + r) * D_ + k4];
        et[(k4 + 0) * 20 + r] = v.x;
        et[(k4 + 1) * 20 + r] = v.y;
        et[(k4 + 2) * 20 + r] = v.z;
        et[(k4 + 3) * 20 + r] = v.w;
    }
    __syncthreads();

    // ---- main: wave = k-slice (64 k), lane = 16 col-quads x 4 row-quads ----
    const int lane = t & 63;
    const int ks = t >> 6;                  // 0..7
    const int kb = ks << 6;
    const int c4 = (lane & 15) << 2;        // 0..60
    const int rq = ((lane >> 4) & 3) << 2;  // 0,4,8,12
    const float* __restrict__ wp = W1 + (half << 18) + (kb << 9) + cb + c4;

    float4 a0 = {0.f, 0.f, 0.f, 0.f}, a1 = {0.f, 0.f, 0.f, 0.f};
    float4 a2 = {0.f, 0.f, 0.f, 0.f}, a3 = {0.f, 0.f, 0.f, 0.f};
#pragma unroll 8
    for (int k = 0; k < 64; ++k) {
        float4 wv = *(const float4*)(wp + (k << 9));
        float4 ev = *(const float4*)&et[(kb + k) * 20 + rq];
        a0.x = fmaf(ev.x, wv.x, a0.x); a0.y = fmaf(ev.x, wv.y, a0.y);
        a0.z = fmaf(ev.x, wv.z, a0.z); a0.w = fmaf(ev.x, wv.w, a0.w);
        a1.x = fmaf(ev.y, wv.x, a1.x); a1.y = fmaf(ev.y, wv.y, a1.y);
        a1.z = fmaf(ev.y, wv.z, a1.z); a1.w = fmaf(ev.y, wv.w, a1.w);
        a2.x = fmaf(ev.z, wv.x, a2.x); a2.y = fmaf(ev.z, wv.y, a2.y);
        a2.z = fmaf(ev.z, wv.z, a2.z); a2.w = fmaf(ev.z, wv.w, a2.w);
        a3.x = fmaf(ev.w, wv.x, a3.x); a3.y = fmaf(ev.w, wv.y, a3.y);
        a3.z = fmaf(ev.w, wv.z, a3.z); a3.w = fmaf(ev.w, wv.w, a3.w);
    }

    // ---- reduce the 8 k-slice partials via LDS overlay on et ----
    __syncthreads();                         // all et reads done
    float* red = et;                         // red[ks][1024], 32KB
    const int ob = (ks << 10) + c4;
    *(float4*)&red[ob + ((rq + 0) << 6)] = a0;
    *(float4*)&red[ob + ((rq + 1) << 6)] = a1;
    *(float4*)&red[ob + ((rq + 2) << 6)] = a2;
    *(float4*)&red[ob + ((rq + 3) << 6)] = a3;
    __syncthreads();

    // thread t -> outputs 2t, 2t+1 (row t>>5, cols (2t)&63)
    float2 s = {0.f, 0.f};
#pragma unroll
    for (int k2 = 0; k2 < 8; ++k2) {
        float2 p = *(const float2*)&red[(k2 << 10) + (t << 1)];
        s.x += p.x; s.y += p.y;
    }
    const int ro = t >> 5, co = (t << 1) & 63;
    if (half) {
        float2 bb = *(const float2*)&b1[cb + co];
        s.x += bb.x; s.y += bb.y;
    }
    *(float2*)&W[((half << 9) + r0 + ro) * D_ + cb + co] = s;
}

// ---------------- K2: fused stats -> cov -> rstd -> gelu-dot -> sigmoid ----
// Round-4 post-mortem: 16x16 tiles @ 66KB LDS -> ~1 block/CU resident, every
// barrier phase serially exposed (VALUBusy 45%, occ 14%). v5: 8x8 pair tiles,
// 2080 blocks x 256 thr (4 waves), 33KB LDS -> 3-4 blocks/CU, cross-block
// phase overlap; per-thread work halves (128 gelu evals). Per-pair summation
// structure IDENTICAL to round 4 (ks=16 k-slices x 8 iters, same stats
// reduce, same formulas) -> bit-identical numerics (absmax at threshold).
// 16 pair-threads (pt: 1 l-row x 4 r-cols) x 16 k-slices (ks, low lane bits).

// gelu_tanh(x) = x * sigmoid(1.5957691*(x + 0.044715 x^3))
// q = log2(exp(-2y)) = x*(A*x^2+B), B = -2*log2e*0.79788456, A = B*0.044715
// x = ((l+r) - mm)*rst*g + be = fmaf(fmaf(s, RST, T2N), g, be), T2N = -mm*rst
#define GELU1(L, R, G, BE, WC, RST, T2N, ACC)                                 \
    do {                                                                      \
        float s_ = (L) + (R);                                                 \
        float x_ = fmaf(fmaf(s_, (RST), (T2N)), (G), (BE));                   \
        float q_ = x_ * fmaf(-0.10294340f, x_ * x_, -2.30220935f);            \
        float e_ = __builtin_amdgcn_exp2f(q_);                                \
        float ge_ = x_ * __builtin_amdgcn_rcpf(1.f + e_);                     \
        ACC = fmaf(ge_, (WC), ACC);                                           \
    } while (0)

#define GELU4(LQ, RQ, RST, T2N, ACC)                                          \
    do {                                                                      \
        GELU1(LQ.x, RQ.x, g4.x, be4.x, w4.x, RST, T2N, ACC);                  \
        GELU1(LQ.y, RQ.y, g4.y, be4.y, w4.y, RST, T2N, ACC);                  \
        GELU1(LQ.z, RQ.z, g4.z, be4.z, w4.z, RST, T2N, ACC);                  \
        GELU1(LQ.w, RQ.w, g4.w, be4.w, w4.w, RST, T2N, ACC);                  \
    } while (0)

#define DOT4(LQ, RQ, ACC)                                                     \
    ACC += LQ.x * RQ.x + LQ.y * RQ.y + LQ.z * RQ.z + LQ.w * RQ.w

#define BFLY(V)                                                               \
    do {                                                                      \
        V += __shfl_xor(V, 1, 64);                                            \
        V += __shfl_xor(V, 2, 64);                                            \
        V += __shfl_xor(V, 4, 64);                                            \
        V += __shfl_xor(V, 8, 64);                                            \
    } while (0)

__global__ __launch_bounds__(256, 4) void k_pair(const float* __restrict__ W,
                                                 const float* __restrict__ gf,
                                                 const float* __restrict__ bef,
                                                 const float* __restrict__ wf,
                                                 const float* __restrict__ b2f,
                                                 float* __restrict__ out) {
    __shared__ float ls[8][516];    // 516 mod 32 = 4 -> reads spread banks
    __shared__ float rs[8][516];
    __shared__ float smean[16];     // rows 0-7: ls, 8-15: rs
    __shared__ float svar[16];

    // decode upper-triangle tile index b -> (I, J), I<=J, 64 tile-rows
    const int b = blockIdx.x;
    int I = (int)((129.0f - sqrtf(16641.0f - 8.0f * (float)b)) * 0.5f);
    if (I < 0) I = 0;
    if (I > 63) I = 63;
#define S_(i) (64 * (i) - ((i) * ((i)-1)) / 2)
    while (S_(I) > b) --I;
    while (S_(I + 1) <= b) ++I;
    const int J = I + (b - S_(I));
#undef S_

    const int t = threadIdx.x;
    const int ks = t & 15;          // k-slice: lane bits 0..3 -> shfl-reducible
    const int pt = t >> 4;          // 0..15 pair-threads
    const int i1 = pt & 7;          // l-row
    const int j4 = (pt >> 3) * 4;   // r-col quad base (0 or 4)
    const int Ibase = I * 8, Jbase = N_ + J * 8;

    // ---- stage raw tiles (coalesced 1KB/row chunks, 4 iters) ----
    for (int x = t; x < 8 * 128; x += 256) {
        int r = x >> 7, c4 = (x & 127) << 2;
        *(float4*)&ls[r][c4] = *(const float4*)&W[(Ibase + r) * D_ + c4];
        *(float4*)&rs[r][c4] = *(const float4*)&W[(Jbase + r) * D_ + c4];
    }
    __syncthreads();

    // ---- per-row mean/var from resident tiles (wave-parallel, 4 rows/wave) --
    {
        const int lane = t & 63, w = t >> 6;
#pragma unroll
        for (int rr = 0; rr < 4; ++rr) {
            const int row = w * 4 + rr;                 // 0..15
            const float* p = (row < 8) ? &ls[row][0] : &rs[row - 8][0];
            float4 a = *(const float4*)&p[lane << 2];
            float4 c = *(const float4*)&p[256 + (lane << 2)];
            float sm = (a.x + a.y) + (a.z + a.w) + (c.x + c.y) + (c.z + c.w);
            float sq = a.x * a.x + a.y * a.y + a.z * a.z + a.w * a.w +
                       c.x * c.x + c.y * c.y + c.z * c.z + c.w * c.w;
#pragma unroll
            for (int off = 32; off > 0; off >>= 1) {
                sm += __shfl_xor(sm, off, 64);
                sq += __shfl_xor(sq, off, 64);
            }
            if (lane == 0) {
                float mu = sm * (1.f / D_);
                smean[row] = mu;
                svar[row] = fmaf(-mu, mu, sq * (1.f / D_));
            }
        }
    }
    __syncthreads();

    // ---- pass A: raw cov-dot (1 l-row x 4 r-rows, named scalar chains) ----
    float cv0 = 0.f, cv1 = 0.f, cv2 = 0.f, cv3 = 0.f;
    for (int it = 0; it < 8; ++it) {
        const int kq = (it * 16 + ks) * 4;
        float4 la = *(float4*)&ls[i1][kq];
        float4 ra = *(float4*)&rs[j4][kq];
        float4 rb = *(float4*)&rs[j4 + 1][kq];
        float4 rc = *(float4*)&rs[j4 + 2][kq];
        float4 rd = *(float4*)&rs[j4 + 3][kq];
        DOT4(la, ra, cv0); DOT4(la, rb, cv1); DOT4(la, rc, cv2); DOT4(la, rd, cv3);
    }
    BFLY(cv0); BFLY(cv1); BFLY(cv2); BFLY(cv3);

    // ---- rstd + mean-shift in-register ----
    // varh = var_l + var_r + cv*(2/D) - 2*ml*mr + eps ; t2n = -(ml+mr)*rst
    const float ml0 = smean[i1];
    const float vl0 = svar[i1];
    const float mr0 = smean[8 + j4],     mr1 = smean[8 + j4 + 1];
    const float mr2 = smean[8 + j4 + 2], mr3 = smean[8 + j4 + 3];
    const float vr0 = svar[8 + j4],     vr1 = svar[8 + j4 + 1];
    const float vr2 = svar[8 + j4 + 2], vr3 = svar[8 + j4 + 3];
    const float rst0 = rsqrtf(vl0 + vr0 + cv0 * (2.f / D_) - 2.f * ml0 * mr0 + 1e-5f);
    const float rst1 = rsqrtf(vl0 + vr1 + cv1 * (2.f / D_) - 2.f * ml0 * mr1 + 1e-5f);
    const float rst2 = rsqrtf(vl0 + vr2 + cv2 * (2.f / D_) - 2.f * ml0 * mr2 + 1e-5f);
    const float rst3 = rsqrtf(vl0 + vr3 + cv3 * (2.f / D_) - 2.f * ml0 * mr3 + 1e-5f);
    const float t2n0 = -(ml0 + mr0) * rst0;
    const float t2n1 = -(ml0 + mr1) * rst1;
    const float t2n2 = -(ml0 + mr2) * rst2;
    const float t2n3 = -(ml0 + mr3) * rst3;

    // ---- pass B: gelu dot over the same resident tiles ----
    float ac0 = 0.f, ac1 = 0.f, ac2 = 0.f, ac3 = 0.f;
    for (int it = 0; it < 8; ++it) {
        const int kq = (it * 16 + ks) * 4;
        float4 g4 = *(const float4*)&gf[kq];
        float4 be4 = *(const float4*)&bef[kq];
        float4 w4 = *(const float4*)&wf[kq];
        float4 la = *(float4*)&ls[i1][kq];
        float4 ra = *(float4*)&rs[j4][kq];
        float4 rb = *(float4*)&rs[j4 + 1][kq];
        float4 rc = *(float4*)&rs[j4 + 2][kq];
        float4 rd = *(float4*)&rs[j4 + 3][kq];
        GELU4(la, ra, rst0, t2n0, ac0); GELU4(la, rb, rst1, t2n1, ac1);
        GELU4(la, rc, rst2, t2n2, ac2); GELU4(la, rd, rst3, t2n3, ac3);
    }
    BFLY(ac0); BFLY(ac1); BFLY(ac2); BFLY(ac3);

    // ---- sigmoid + mirrored store (ks==0 lane of each pair-thread) ----
    if (ks == 0) {
        const float bb = b2f[0];
        const float z0 = __builtin_amdgcn_rcpf(
            1.f + __builtin_amdgcn_exp2f(-1.44269504f * (ac0 + bb)));
        const float z1 = __builtin_amdgcn_rcpf(
            1.f + __builtin_amdgcn_exp2f(-1.44269504f * (ac1 + bb)));
        const float z2 = __builtin_amdgcn_rcpf(
            1.f + __builtin_amdgcn_exp2f(-1.44269504f * (ac2 + bb)));
        const float z3 = __builtin_amdgcn_rcpf(
            1.f + __builtin_amdgcn_exp2f(-1.44269504f * (ac3 + bb)));
        const int gi = Ibase + i1;
        const int gj0 = (Jbase - N_) + j4;
        if (I < J) {
            float4 o0 = {z0, z1, z2, z3};
            *(float4*)&out[gi * N_ + gj0] = o0;
            out[gj0 * N_ + gi] = z0;
            out[(gj0 + 1) * N_ + gi] = z1;
            out[(gj0 + 2) * N_ + gi] = z2;
            out[(gj0 + 3) * N_ + gi] = z3;
        } else {  // diagonal tile: only pairs gi<=gj are valid
            if (gi <= gj0)     { out[gi * N_ + gj0] = z0;       out[gj0 * N_ + gi] = z0; }
            if (gi <= gj0 + 1) { out[gi * N_ + gj0 + 1] = z1;   out[(gj0 + 1) * N_ + gi] = z1; }
            if (gi <= gj0 + 2) { out[gi * N_ + gj0 + 2] = z2;   out[(gj0 + 2) * N_ + gi] = z2; }
            if (gi <= gj0 + 3) { out[gi * N_ + gj0 + 3] = z3;   out[(gj0 + 3) * N_ + gi] = z3; }
        }
    }
}

extern "C" void kernel_launch(void* const* d_in, const int* in_sizes, int n_in,
                              void* d_out, int out_size, void* d_ws, size_t ws_size,
                              hipStream_t stream) {
    const float* E     = (const float*)d_in[0];
    const float* W1    = (const float*)d_in[1];
    const float* b1    = (const float*)d_in[2];
    const float* gamma = (const float*)d_in[3];
    const float* beta  = (const float*)d_in[4];
    const float* w2    = (const float*)d_in[5];
    const float* b2    = (const float*)d_in[6];
    float* out = (float*)d_out;

    float* lcrc = (float*)d_ws;       // [1024][512]: rows 0..511 lc, 512..1023 rc(+b1)

    k_gemm<<<512, 512, 0, stream>>>(E, W1, b1, lcrc);
    k_pair<<<2080, 256, 0, stream>>>(lcrc, gamma, beta, w2, b2, out);
}